// Round 2
// baseline (255.425 us; speedup 1.0000x reference)
//
#include <hip/hip_runtime.h>
#include <hip/hip_bf16.h>

// Problem constants (from reference)
#define BB 2
#define TT 1024
#define CC 2048
#define NCH 8
#define KLAT 32
#define NKV 4
#define NREP 4
#define DD 128
#define MROWS (BB*TT)          // 2048
#define CSROWS (BB*NCH*KLAT)   // 512
#define NBUCKET 16             // B * NCH
#define TTILE 8                // tokens per attention tile
#define MAXTILES (MROWS/TTILE + NBUCKET)   // 272

typedef unsigned short u16;
typedef __attribute__((ext_vector_type(8))) short bf16x8;   // MFMA A/B frag (4 VGPRs)
typedef __attribute__((ext_vector_type(4))) float f32x4;    // MFMA C/D frag
typedef __attribute__((ext_vector_type(8))) u16 u16x8;

__device__ __forceinline__ u16 f2bf(float f) {
    unsigned int u = __builtin_bit_cast(unsigned int, f);
    u = (u + 0x7FFFu + ((u >> 16) & 1u)) >> 16;   // RNE; inputs finite
    return (u16)u;
}

// async global->LDS, 16B per lane. LDS dest = wave-uniform base + lane*16.
__device__ __forceinline__ void glds16(const u16* g, u16* l) {
    __builtin_amdgcn_global_load_lds(
        (const __attribute__((address_space(1))) void*)g,
        (__attribute__((address_space(3))) void*)l, 16, 0, 0);
}

// ---------------- elementwise fp32 -> bf16 ----------------
__global__ void __launch_bounds__(256)
cvt_bf16_kernel(const float* __restrict__ in, u16* __restrict__ out, int n) {
    int i = (blockIdx.x * 256 + threadIdx.x) * 8;
    if (i >= n) return;
    float4 a = *(const float4*)(in + i);
    float4 b = *(const float4*)(in + i + 4);
    u16x8 o;
    o[0]=f2bf(a.x); o[1]=f2bf(a.y); o[2]=f2bf(a.z); o[3]=f2bf(a.w);
    o[4]=f2bf(b.x); o[5]=f2bf(b.y); o[6]=f2bf(b.z); o[7]=f2bf(b.w);
    *(u16x8*)(out + i) = o;
}

// ---------------- transpose + convert: in (R x C) fp32 -> out (C x R) bf16 ----------------
__global__ void __launch_bounds__(256)
tcvt_kernel(const float* __restrict__ in, u16* __restrict__ out, int R, int C) {
    __shared__ u16 tile[64][65];
    const int c0 = blockIdx.x * 64;
    const int r0 = blockIdx.y * 64;
    const int tid = threadIdx.x;
    const int tx = tid & 15;
    const int ty = tid >> 4;
#pragma unroll
    for (int p = 0; p < 4; ++p) {
        int r = p * 16 + ty;
        float4 v = *(const float4*)(in + (size_t)(r0 + r) * C + c0 + tx * 4);
        tile[tx*4+0][r] = f2bf(v.x);
        tile[tx*4+1][r] = f2bf(v.y);
        tile[tx*4+2][r] = f2bf(v.z);
        tile[tx*4+3][r] = f2bf(v.w);
    }
    __syncthreads();
    const int oc = tid >> 2;
    const int op = tid & 3;
    u16* dst = out + (size_t)(c0 + oc) * R + r0 + op * 16;
    u16x8 v0, v1;
#pragma unroll
    for (int j = 0; j < 8; ++j) { v0[j] = tile[oc][op*16 + j]; v1[j] = tile[oc][op*16 + 8 + j]; }
    *(u16x8*)dst = v0;
    *(u16x8*)(dst + 8) = v1;
}

// ---------------- bf16 GEMM with global_load_lds staging (m97 2-barrier) ----------------
// A: M x K bf16 row-major; Bt: N x K bf16 row-major; C: M x N.
// OUT: 1 = f32 * tanh(gate), 2 = bf16, 3 = atomic f32 (split-K)
template<int BM, int BN, int OUT>
__global__ void __launch_bounds__(256)
gemm_glds_kernel(const u16* __restrict__ A, const u16* __restrict__ Bt,
                 void* __restrict__ Cp, int M, int N, int K, int kChunk,
                 const float* __restrict__ gate)
{
    constexpr int BK = 32;
    __shared__ u16 As[BM * BK];
    __shared__ u16 Bs[BN * BK];
    const int tid  = threadIdx.x;
    const int wave = tid >> 6;
    const int lane = tid & 63;
    const int m0   = blockIdx.x * BM;
    const int n0   = blockIdx.y * BN;
    const int kbeg = blockIdx.z * kChunk;
    constexpr int WM = BM / 2, WN = BN / 2;
    constexpr int MI = WM / 16, NI = WN / 16;
    const int wm = (wave & 1) * WM;
    const int wn = (wave >> 1) * WN;
    const int ml = lane & 15;
    const int quad = lane >> 4;

    f32x4 acc[MI][NI];
#pragma unroll
    for (int i = 0; i < MI; ++i)
#pragma unroll
        for (int j = 0; j < NI; ++j) acc[i][j] = (f32x4){0.f, 0.f, 0.f, 0.f};

    constexpr int RA = (BM * BK) / 2048;   // staging rounds (2048 u16 per round)
    constexpr int RB = (BN * BK) / 2048;
    const u16* aptr = A  + (size_t)(m0 + (tid >> 2)) * K + kbeg + (tid & 3) * 8;
    const u16* bptr = Bt + (size_t)(n0 + (tid >> 2)) * K + kbeg + (tid & 3) * 8;
    u16* As_w = As + wave * 512;   // wave-uniform LDS base (1024 B per wave)
    u16* Bs_w = Bs + wave * 512;

    for (int k0 = 0; k0 < kChunk; k0 += BK) {
        __syncthreads();   // previous tile's frags consumed
#pragma unroll
        for (int p = 0; p < RA; ++p) glds16(aptr + (size_t)p * 64 * K + k0, As_w + p * 2048);
#pragma unroll
        for (int p = 0; p < RB; ++p) glds16(bptr + (size_t)p * 64 * K + k0, Bs_w + p * 2048);
        __syncthreads();   // drains vmcnt -> LDS data visible
        bf16x8 afr[MI], bfr[NI];
#pragma unroll
        for (int i = 0; i < MI; ++i)
            afr[i] = *(const bf16x8*)&As[(wm + i * 16 + ml) * BK + quad * 8];
#pragma unroll
        for (int j = 0; j < NI; ++j)
            bfr[j] = *(const bf16x8*)&Bs[(wn + j * 16 + ml) * BK + quad * 8];
#pragma unroll
        for (int i = 0; i < MI; ++i)
#pragma unroll
            for (int j = 0; j < NI; ++j)
                acc[i][j] = __builtin_amdgcn_mfma_f32_16x16x32_bf16(afr[i], bfr[j], acc[i][j], 0, 0, 0);
    }

    float scl = 1.0f;
    if (OUT == 1) scl = tanhf(gate[0]);
    // C/D layout (m89/m91): col = lane&15, row = quad*4 + reg
#pragma unroll
    for (int i = 0; i < MI; ++i)
#pragma unroll
        for (int j = 0; j < NI; ++j)
#pragma unroll
            for (int rr = 0; rr < 4; ++rr) {
                int gr = m0 + wm + i * 16 + quad * 4 + rr;
                int gc = n0 + wn + j * 16 + ml;
                float val = acc[i][j][rr];
                if (OUT == 1)      ((float*)Cp)[(size_t)gr * N + gc] = val * scl;
                else if (OUT == 2) ((u16*)Cp)[(size_t)gr * N + gc] = f2bf(val);
                else               atomicAdd((float*)Cp + (size_t)gr * N + gc, val);
            }
}

// ---------------- counting sort of tokens by (b, channel) ----------------
__global__ void __launch_bounds__(256)
sort_kernel(const int* __restrict__ cmask, int* __restrict__ sorted,
            int4* __restrict__ tiles, int* __restrict__ ntiles)
{
    __shared__ int cnt[NBUCKET], cur[NBUCKET];
    int t = threadIdx.x;
    if (t < NBUCKET) cnt[t] = 0;
    __syncthreads();
    for (int i = t; i < MROWS; i += 256) {
        int bkt = ((i >> 10) << 3) | cmask[i];
        atomicAdd(&cnt[bkt], 1);
    }
    __syncthreads();
    if (t == 0) {
        int off = 0, nt = 0;
        for (int b2 = 0; b2 < NBUCKET; ++b2) {
            cur[b2] = off;
            for (int o = 0; o < cnt[b2]; o += TTILE)
                tiles[nt++] = make_int4(b2, off + o, min(TTILE, cnt[b2] - o), 0);
            off += cnt[b2];
        }
        *ntiles = nt;
    }
    __syncthreads();
    for (int i = t; i < MROWS; i += 256) {
        int bkt = ((i >> 10) << 3) | cmask[i];
        int pos = atomicAdd(&cur[bkt], 1);
        sorted[pos] = i;
    }
}

// ---------------- kv fp32 -> kb bf16 (as-is) + vt bf16 (transposed) ----------------
// kvf: (512 rows = (b,n,lat), 1024 cols = [k: g*128+d | v: g*128+d]) fp32
// kb:  (512 rows, 512 cols) bf16;  vt: ((b,n,g), d, lat) bf16
__global__ void __launch_bounds__(256)
kvcvt_kernel(const float* __restrict__ kvf, u16* __restrict__ kb, u16* __restrict__ vt)
{
    const int bn = blockIdx.x >> 2;
    const int g  = blockIdx.x & 3;
    const int t  = threadIdx.x;
#pragma unroll
    for (int i = 0; i < 16; ++i) {
        int flat = i * 256 + t;           // 0..4095
        int lat = flat >> 7, d = flat & 127;
        kb[(size_t)(bn * 32 + lat) * 512 + g * 128 + d] =
            f2bf(kvf[(size_t)(bn * 32 + lat) * 1024 + g * 128 + d]);
        int d2 = flat >> 5, lat2 = flat & 31;
        vt[((size_t)bn * 4 + g) * 4096 + d2 * 32 + lat2] =
            f2bf(kvf[(size_t)(bn * 32 + lat2) * 1024 + 512 + g * 128 + d2]);
    }
}

// ---------------- MFMA attention: one (tile of 8 same-channel tokens, group g) per wave ----------------
// qb: (2048, 2048) bf16, col = g*512 + r*128 + d
// kb: (512 rows=(b,n,lat), 512 cols=g*128+d) bf16
// vt: ((b,n,g), d=128, lat=32) bf16
// yb: (2048, 2048) bf16 (same col layout as qb)
#define KSTR 136   // k_lds row stride (u16): 272 B, 16B-aligned, odd*16
#define VSTR 40    // v_lds / p_lds row stride (u16): 80 B
__global__ void __launch_bounds__(64)
attn_mfma_kernel(const u16* __restrict__ qb, const u16* __restrict__ kb,
                 const u16* __restrict__ vt, const int* __restrict__ sorted,
                 const int4* __restrict__ tiles, const int* __restrict__ ntiles,
                 u16* __restrict__ yb)
{
    const int tile = blockIdx.x;
    if (tile >= *ntiles) return;
    const int g = blockIdx.y;
    const int4 td = tiles[tile];
    const int bucket = td.x, start = td.y, cnt = td.z;
    const int lane = threadIdx.x;
    const int ml = lane & 15, quad = lane >> 4;

    __shared__ u16 k_lds[32 * KSTR];    // K_g: (lat, d)
    __shared__ u16 v_lds[128 * VSTR];   // V_g^T: (d, lat)
    __shared__ u16 p_lds[32 * VSTR];    // P: (m, lat), m = i*16 + row
    __shared__ int tok_s[TTILE];

    if (lane < TTILE) tok_s[lane] = (lane < cnt) ? sorted[start + lane] : -1;

    // stage K_g (32x128) and V_g^T (128x32): 8 KB each, 8 rounds of 1 KB
    {
        const u16* ksrc = kb + (size_t)bucket * 32 * 512 + g * 128;
        const u16* vsrc = vt + ((size_t)bucket * 4 + g) * 4096;
#pragma unroll
        for (int rr = 0; rr < 8; ++rr) {
            int f = rr * 64 + lane;
            int krow = f >> 4, kc = (f & 15) * 8;
            *(u16x8*)&k_lds[krow * KSTR + kc] = *(const u16x8*)(ksrc + (size_t)krow * 512 + kc);
            int vd = f >> 2, vc = (f & 3) * 8;
            *(u16x8*)&v_lds[vd * VSTR + vc] = *(const u16x8*)(vsrc + (size_t)f * 8);
        }
    }
    __syncthreads();

    // scores: D[m][lat], m-tile i: tok = tok_s[m&7], r = i*2 + (m>>3); K=128 in 4 steps
    f32x4 sc[2][2];
#pragma unroll
    for (int i = 0; i < 2; ++i)
#pragma unroll
        for (int j = 0; j < 2; ++j) sc[i][j] = (f32x4){0.f, 0.f, 0.f, 0.f};
    const int tokA = tok_s[ml & 7];
    const u16* qrow = qb + (size_t)(tokA >= 0 ? tokA : 0) * 2048 + g * 512 + (ml >> 3) * 128;
#pragma unroll
    for (int s = 0; s < 4; ++s) {
        bf16x8 bfr0 = *(const bf16x8*)&k_lds[ml * KSTR + s * 32 + quad * 8];
        bf16x8 bfr1 = *(const bf16x8*)&k_lds[(16 + ml) * KSTR + s * 32 + quad * 8];
#pragma unroll
        for (int i = 0; i < 2; ++i) {
            bf16x8 afr = *(const bf16x8*)(qrow + i * 256 + s * 32 + quad * 8);
            sc[i][0] = __builtin_amdgcn_mfma_f32_16x16x32_bf16(afr, bfr0, sc[i][0], 0, 0, 0);
            sc[i][1] = __builtin_amdgcn_mfma_f32_16x16x32_bf16(afr, bfr1, sc[i][1], 0, 0, 0);
        }
    }

    // per-row softmax over 32 latents; row = quad*4+reg, cols split l16 x {j=0,1}
    const float scale = 0.088388347648318447f;   // 1/sqrt(128)
#pragma unroll
    for (int i = 0; i < 2; ++i)
#pragma unroll
        for (int reg = 0; reg < 4; ++reg) {
            float s0 = sc[i][0][reg] * scale;
            float s1 = sc[i][1][reg] * scale;
            float mx = fmaxf(s0, s1);
            mx = fmaxf(mx, __shfl_xor(mx, 1));
            mx = fmaxf(mx, __shfl_xor(mx, 2));
            mx = fmaxf(mx, __shfl_xor(mx, 4));
            mx = fmaxf(mx, __shfl_xor(mx, 8));
            float e0 = __expf(s0 - mx), e1 = __expf(s1 - mx);
            float sm = e0 + e1;
            sm += __shfl_xor(sm, 1);
            sm += __shfl_xor(sm, 2);
            sm += __shfl_xor(sm, 4);
            sm += __shfl_xor(sm, 8);
            float inv = 1.0f / sm;
            int prow = i * 16 + quad * 4 + reg;
            p_lds[prow * VSTR + ml]      = f2bf(e0 * inv);
            p_lds[prow * VSTR + 16 + ml] = f2bf(e1 * inv);
        }
    __syncthreads();

    // PV: y[m][d] = sum_lat P[m][lat] * V[lat][d]; K=32 single MFMA step
    bf16x8 pfr[2], vfr[8];
    pfr[0] = *(const bf16x8*)&p_lds[ml * VSTR + quad * 8];
    pfr[1] = *(const bf16x8*)&p_lds[(16 + ml) * VSTR + quad * 8];
#pragma unroll
    for (int j = 0; j < 8; ++j)
        vfr[j] = *(const bf16x8*)&v_lds[(j * 16 + ml) * VSTR + quad * 8];
#pragma unroll
    for (int i = 0; i < 2; ++i)
#pragma unroll
        for (int j = 0; j < 8; ++j) {
            f32x4 o = (f32x4){0.f, 0.f, 0.f, 0.f};
            o = __builtin_amdgcn_mfma_f32_16x16x32_bf16(pfr[i], vfr[j], o, 0, 0, 0);
#pragma unroll
            for (int reg = 0; reg < 4; ++reg) {
                int m = quad * 4 + reg;
                int tok = tok_s[m & 7];
                if (tok >= 0) {
                    int r = i * 2 + (m >> 3);
                    yb[(size_t)tok * 2048 + g * 512 + r * 128 + j * 16 + ml] = f2bf(o[reg]);
                }
            }
        }
}

extern "C" void kernel_launch(void* const* d_in, const int* in_sizes, int n_in,
                              void* d_out, int out_size, void* d_ws, size_t ws_size,
                              hipStream_t stream) {
    const float* x    = (const float*)d_in[0];
    const float* cs   = (const float*)d_in[1];
    const int*   cm   = (const int*)d_in[2];
    const float* Wq   = (const float*)d_in[3];
    const float* Wk   = (const float*)d_in[4];
    const float* Wv   = (const float*)d_in[5];
    const float* Wo   = (const float*)d_in[6];
    const float* gate = (const float*)d_in[7];
    float* out = (float*)d_out;

    // workspace layout (16B aligned)
    char* w = (char*)d_ws;
    u16* xb   = (u16*)w;  w += (size_t)MROWS * CC * 2;
    u16* wqt  = (u16*)w;  w += (size_t)CC * CC * 2;
    u16* wkvt = (u16*)w;  w += (size_t)1024 * CC * 2;
    u16* wot  = (u16*)w;  w += (size_t)CC * CC * 2;
    u16* csb  = (u16*)w;  w += (size_t)CSROWS * CC * 2;
    u16* yb   = (u16*)w;  w += (size_t)MROWS * CC * 2;
    u16* qb   = (u16*)w;  w += (size_t)MROWS * CC * 2;
    float* kvf = (float*)w; w += (size_t)CSROWS * 1024 * 4;
    u16* kb   = (u16*)w;  w += (size_t)CSROWS * 512 * 2;
    u16* vt   = (u16*)w;  w += (size_t)64 * 128 * 32 * 2;
    int* sorted = (int*)w; w += (size_t)MROWS * 4;
    int4* tiles = (int4*)w; w += (size_t)MAXTILES * 16;
    int* ntiles = (int*)w;  w += 16;

    hipMemsetAsync(kvf, 0, (size_t)CSROWS * 1024 * 4, stream);

    sort_kernel<<<1, 256, 0, stream>>>(cm, sorted, tiles, ntiles);
    cvt_bf16_kernel<<<(MROWS * CC) / 2048, 256, 0, stream>>>(x, xb, MROWS * CC);
    cvt_bf16_kernel<<<(CSROWS * CC) / 2048, 256, 0, stream>>>(cs, csb, CSROWS * CC);
    tcvt_kernel<<<dim3(CC / 64, CC / 64), 256, 0, stream>>>(Wq, wqt, CC, CC);
    tcvt_kernel<<<dim3(512 / 64, CC / 64), 256, 0, stream>>>(Wk, wkvt, CC, 512);
    tcvt_kernel<<<dim3(512 / 64, CC / 64), 256, 0, stream>>>(Wv, wkvt + (size_t)512 * CC, CC, 512);
    tcvt_kernel<<<dim3(CC / 64, CC / 64), 256, 0, stream>>>(Wo, wot, CC, CC);

    // q = x @ Wq -> bf16   (2048x2048x2048), 128x64 tiles, grid 512
    gemm_glds_kernel<128, 64, 2><<<dim3(MROWS / 128, CC / 64), 256, 0, stream>>>(
        xb, wqt, qb, MROWS, CC, CC, CC, nullptr);
    // kv = cs @ [Wk|Wv] -> fp32 atomic (512x1024x2048), split-K=4
    gemm_glds_kernel<64, 64, 3><<<dim3(CSROWS / 64, 1024 / 64, 4), 256, 0, stream>>>(
        csb, wkvt, kvf, CSROWS, 1024, CC, CC / 4, nullptr);
    kvcvt_kernel<<<64, 256, 0, stream>>>(kvf, kb, vt);
    // attention
    attn_mfma_kernel<<<dim3(MAXTILES, 4), 64, 0, stream>>>(qb, kb, vt, sorted, tiles, ntiles, yb);
    // out = (y @ Wo) * tanh(gate)   (2048x2048x2048)
    gemm_glds_kernel<128, 64, 1><<<dim3(MROWS / 128, CC / 64), 256, 0, stream>>>(
        yb, wot, out, MROWS, CC, CC, CC, gate);
}